// Round 5
// baseline (461.057 us; speedup 1.0000x reference)
//
#include <hip/hip_runtime.h>
#include <hip/hip_bf16.h>
#include <math.h>

#define N_NODES 100000
#define N_EDGES 1250000
#define D_IN    64
#define D_HID   64
#define N_CLS   40

#define SCAN_NBLK ((N_NODES + 255) / 256)   // 391
#define NPART    8
#define PART_SZ  ((N_NODES + NPART - 1) / NPART)   // 12500
#define NCHUNK   128                                // fill/hist: 128 chunks x 8 parts

typedef unsigned int uint;

static __device__ __forceinline__ uint pack_bf16x2(float a, float b) {
    unsigned short ua = __builtin_bit_cast(unsigned short, __float2bfloat16(a));
    unsigned short ub = __builtin_bit_cast(unsigned short, __float2bfloat16(b));
    return (uint)ua | ((uint)ub << 16);
}

// ---------------------------------------------------------------------------
// CSR build, XCD-partitioned: block handles partition (blockIdx & 7) only,
// so cursor atomics and csr_src scatter-writes stay in one XCD's L2.
// ---------------------------------------------------------------------------
__global__ __launch_bounds__(256) void hist_part(
    const int* __restrict__ dst, int* __restrict__ hist, int n_edges)
{
    const int part  = blockIdx.x & 7;
    const int chunk = blockIdx.x >> 3;
    const int per   = (n_edges + NCHUNK - 1) / NCHUNK;
    const int e0 = chunk * per;
    const int e1 = (e0 + per < n_edges) ? e0 + per : n_edges;
    const int lo = part * PART_SZ, hi = lo + PART_SZ;
    for (int e = e0 + threadIdx.x; e < e1; e += 256) {
        int d = dst[e];
        if (d >= lo && d < hi) atomicAdd(&hist[d], 1);
    }
}

__global__ __launch_bounds__(256) void fill_part(
    const int* __restrict__ src, const int* __restrict__ dst,
    int* __restrict__ cursor, int* __restrict__ csr_src, int n_edges)
{
    const int part  = blockIdx.x & 7;
    const int chunk = blockIdx.x >> 3;
    const int per   = (n_edges + NCHUNK - 1) / NCHUNK;
    const int e0 = chunk * per;
    const int e1 = (e0 + per < n_edges) ? e0 + per : n_edges;
    const int lo = part * PART_SZ, hi = lo + PART_SZ;
    for (int e = e0 + threadIdx.x; e < e1; e += 256) {
        int d = dst[e];
        if (d >= lo && d < hi) {
            int pos = atomicAdd(&cursor[d], 1);
            csr_src[pos] = src[e];
        }
    }
}

__global__ __launch_bounds__(256) void scan_block_sums(
    const int* __restrict__ hist, int* __restrict__ partial, int n)
{
    __shared__ int s[256];
    int i = blockIdx.x * 256 + threadIdx.x;
    s[threadIdx.x] = (i < n) ? hist[i] : 0;
    __syncthreads();
    for (int off = 128; off > 0; off >>= 1) {
        if (threadIdx.x < off) s[threadIdx.x] += s[threadIdx.x + off];
        __syncthreads();
    }
    if (threadIdx.x == 0) partial[blockIdx.x] = s[0];
}

__global__ __launch_bounds__(512) void scan_partials(
    int* __restrict__ partial, int nblk)
{
    __shared__ int s[512];
    int t = threadIdx.x;
    s[t] = (t < nblk) ? partial[t] : 0;
    __syncthreads();
    for (int off = 1; off < 512; off <<= 1) {
        int u = (t >= off) ? s[t - off] : 0;
        __syncthreads();
        s[t] += u;
        __syncthreads();
    }
    if (t < nblk) partial[t] = s[t];   // inclusive
}

__global__ __launch_bounds__(256) void scan_final(
    const int* __restrict__ hist, const int* __restrict__ partial_incl,
    int* __restrict__ row_ptr, int* __restrict__ cursor, int n, int n_edges)
{
    __shared__ int s[256];
    int t = threadIdx.x;
    int i = blockIdx.x * 256 + t;
    int v = (i < n) ? hist[i] : 0;
    s[t] = v;
    __syncthreads();
    for (int off = 1; off < 256; off <<= 1) {
        int u = (t >= off) ? s[t - off] : 0;
        __syncthreads();
        s[t] += u;
        __syncthreads();
    }
    int excl = s[t] - v;
    int base = (blockIdx.x > 0) ? partial_incl[blockIdx.x - 1] : 0;
    if (i < n) {
        row_ptr[i] = base + excl;
        cursor[i]  = base + excl;
    }
    if (i == 0) row_ptr[n] = n_edges;
}

// ---------------------------------------------------------------------------
// GEMM 1 (dual): y1 = bf16(x @ W1_l), r1 = bf16(x @ W1_r + b1).
// Interleaved LDS weights so the per-k pair fuses into ds_read2_b32.
// ---------------------------------------------------------------------------
__global__ __launch_bounds__(256, 4) void gemm1(
    const float* __restrict__ x,
    const float* __restrict__ W_l, const float* __restrict__ W_r,
    const float* __restrict__ b,
    __hip_bfloat16* __restrict__ y1, __hip_bfloat16* __restrict__ r1,
    int n_nodes)
{
    __shared__ float sW[64 * 128];   // [k][0..63]=Wl, [k][64..127]=Wr
    for (int i = threadIdx.x; i < 64 * 64; i += 256) {
        int k = i >> 6, c = i & 63;
        sW[k * 128 + c]      = W_l[i];
        sW[k * 128 + 64 + c] = W_r[i];
    }
    __syncthreads();
    const int lane = threadIdx.x & 63;
    const float bv = b[lane];
    const int wave = blockIdx.x * 4 + (threadIdx.x >> 6);
    const int nw   = gridDim.x * 4;
    for (int node = wave; node < n_nodes; node += nw) {
        int xi = __float_as_int(x[(size_t)node * 64 + lane]);
        float accL = 0.0f, accR = bv;
        #pragma unroll
        for (int k = 0; k < 64; ++k) {
            float s = __int_as_float(__builtin_amdgcn_readlane(xi, k));
            accL += s * sW[k * 128 + lane];
            accR += s * sW[k * 128 + 64 + lane];
        }
        y1[(size_t)node * 64 + lane] = __float2bfloat16(accL);
        r1[(size_t)node * 64 + lane] = __float2bfloat16(accR);
    }
}

// ---------------------------------------------------------------------------
// GEMM 2 (dual): y2 = bf16(h @ W2_l), r2 = bf16(h @ W2_r + b2).  64 -> 40.
// ---------------------------------------------------------------------------
__global__ __launch_bounds__(256, 4) void gemm2(
    const __hip_bfloat16* __restrict__ h,
    const float* __restrict__ W_l, const float* __restrict__ W_r,
    const float* __restrict__ b,
    __hip_bfloat16* __restrict__ y2, __hip_bfloat16* __restrict__ r2,
    int n_nodes)
{
    __shared__ float sW[64 * 128];   // [k][0..39]=Wl, [k][64..103]=Wr
    for (int i = threadIdx.x; i < 64 * N_CLS; i += 256) {
        int k = i / N_CLS, c = i % N_CLS;
        sW[k * 128 + c]      = W_l[i];
        sW[k * 128 + 64 + c] = W_r[i];
    }
    __syncthreads();
    const int lane = threadIdx.x & 63;
    const int cl   = lane < N_CLS ? lane : N_CLS - 1;
    const float bv = b[cl];
    const int wave = blockIdx.x * 4 + (threadIdx.x >> 6);
    const int nw   = gridDim.x * 4;
    for (int node = wave; node < n_nodes; node += nw) {
        int hi = __float_as_int((float)h[(size_t)node * 64 + lane]);
        float accL = 0.0f, accR = bv;
        #pragma unroll
        for (int k = 0; k < 64; ++k) {
            float s = __int_as_float(__builtin_amdgcn_readlane(hi, k));
            accL += s * sW[k * 128 + cl];
            accR += s * sW[k * 128 + 64 + cl];
        }
        if (lane < N_CLS) {
            y2[(size_t)node * N_CLS + lane] = __float2bfloat16(accL);
            r2[(size_t)node * N_CLS + lane] = __float2bfloat16(accR);
        }
    }
}

// ---------------------------------------------------------------------------
// Gather 1: h = relu( mean(y1[src]) + r1[node] ).  Pure gather + epilogue.
// 4 edges per wave-load: 16 lanes x 8 B per 128 B row.
// ---------------------------------------------------------------------------
__global__ __launch_bounds__(256, 4) void gather1(
    const __hip_bfloat16* __restrict__ y1,   // [N+1][64], row N zeroed
    const __hip_bfloat16* __restrict__ r1,   // [N][64]
    const int* __restrict__ row_ptr, const int* __restrict__ csr_src,
    __hip_bfloat16* __restrict__ h, int n_nodes)
{
    const int lane = threadIdx.x & 63;
    const int q4  = (lane >> 4) * 4;      // bpermute byte-sel for quad id
    const int pre = (lane & 15) * 8;      // byte offset within 128 B row
    const char* y1c = (const char*)y1;

    const int wave = blockIdx.x * 4 + (threadIdx.x >> 6);
    const int nw   = gridDim.x * 4;

    for (int node = wave; node < n_nodes; node += nw) {
        const int n0  = row_ptr[node];
        const int deg = row_ptr[node + 1] - n0;
        float a0 = 0.f, a1 = 0.f, a2 = 0.f, a3 = 0.f;
        int base = n0, rem = deg;
        while (rem > 0) {
            int cnt = rem < 64 ? rem : 64;
            int idx = csr_src[base + lane];          // slack past N_EDGES
            if (lane >= cnt) idx = n_nodes;          // -> zero dummy row
            int groups = (cnt + 7) & ~7;             // round to 8 edges
            for (int e = 0; e < groups; e += 8) {
                int sel0 = __builtin_amdgcn_ds_bpermute(e * 4 + q4, idx);
                int sel1 = __builtin_amdgcn_ds_bpermute(e * 4 + 16 + q4, idx);
                uint2 d0 = *(const uint2*)(y1c + ((size_t)(uint)sel0 * 128u + (uint)pre));
                uint2 d1 = *(const uint2*)(y1c + ((size_t)(uint)sel1 * 128u + (uint)pre));
                a0 += __uint_as_float(d0.x << 16);
                a1 += __uint_as_float(d0.x & 0xffff0000u);
                a2 += __uint_as_float(d0.y << 16);
                a3 += __uint_as_float(d0.y & 0xffff0000u);
                a0 += __uint_as_float(d1.x << 16);
                a1 += __uint_as_float(d1.x & 0xffff0000u);
                a2 += __uint_as_float(d1.y << 16);
                a3 += __uint_as_float(d1.y & 0xffff0000u);
            }
            base += cnt; rem -= cnt;
        }
        // reduce the 4 quad replicas
        a0 += __shfl_xor(a0, 16); a0 += __shfl_xor(a0, 32);
        a1 += __shfl_xor(a1, 16); a1 += __shfl_xor(a1, 32);
        a2 += __shfl_xor(a2, 16); a2 += __shfl_xor(a2, 32);
        a3 += __shfl_xor(a3, 16); a3 += __shfl_xor(a3, 32);

        // root row (quad layout: channels 4*(lane&15)+j)
        uint2 rr = *(const uint2*)((const char*)r1 + ((size_t)node * 128u + (uint)pre));
        float r0 = __uint_as_float(rr.x << 16);
        float r1v = __uint_as_float(rr.x & 0xffff0000u);
        float r2v = __uint_as_float(rr.y << 16);
        float r3 = __uint_as_float(rr.y & 0xffff0000u);

        float inv = 1.0f / (float)(deg > 1 ? deg : 1);
        float v0 = a0 * inv + r0;  v0 = v0 > 0.f ? v0 : 0.f;
        float v1 = a1 * inv + r1v; v1 = v1 > 0.f ? v1 : 0.f;
        float v2 = a2 * inv + r2v; v2 = v2 > 0.f ? v2 : 0.f;
        float v3 = a3 * inv + r3;  v3 = v3 > 0.f ? v3 : 0.f;

        if (lane < 16) {
            uint2 o;
            o.x = pack_bf16x2(v0, v1);
            o.y = pack_bf16x2(v2, v3);
            *(uint2*)((char*)h + ((size_t)node * 128u + (uint)pre)) = o;
        }
    }
}

// ---------------------------------------------------------------------------
// Gather 2: out = logsoftmax( mean(y2[src]) + r2[node] ).
// 2 edges per wave-load: 20 of each 32 lanes x dword on 80 B rows.
// ---------------------------------------------------------------------------
__global__ __launch_bounds__(256, 4) void gather2(
    const __hip_bfloat16* __restrict__ y2,   // [N+1][40], row N zeroed
    const __hip_bfloat16* __restrict__ r2,   // [N][40]
    const int* __restrict__ row_ptr, const int* __restrict__ csr_src,
    float* __restrict__ out, int n_nodes)
{
    const int lane  = threadIdx.x & 63;
    const int lpair = lane & 31;                      // 0..31; active < 20
    const int p2    = (lane >> 5) * 4;                // bpermute sel: half id
    const int pre2  = (lpair < 20 ? lpair : 19) * 4;  // byte off in 80 B row
    const char* y2c = (const char*)y2;

    const int wave = blockIdx.x * 4 + (threadIdx.x >> 6);
    const int nw   = gridDim.x * 4;

    for (int node = wave; node < n_nodes; node += nw) {
        const int n0  = row_ptr[node];
        const int deg = row_ptr[node + 1] - n0;
        float a0 = 0.f, a1 = 0.f;
        int base = n0, rem = deg;
        while (rem > 0) {
            int cnt = rem < 64 ? rem : 64;
            int idx = csr_src[base + lane];
            if (lane >= cnt) idx = n_nodes;
            int groups = (cnt + 3) & ~3;            // round to 4 edges
            for (int e = 0; e < groups; e += 4) {
                int sel0 = __builtin_amdgcn_ds_bpermute(e * 4 + p2, idx);
                int sel1 = __builtin_amdgcn_ds_bpermute(e * 4 + 8 + p2, idx);
                uint d0 = *(const uint*)(y2c + ((size_t)(uint)sel0 * 80u + (uint)pre2));
                uint d1 = *(const uint*)(y2c + ((size_t)(uint)sel1 * 80u + (uint)pre2));
                a0 += __uint_as_float(d0 << 16);
                a1 += __uint_as_float(d0 & 0xffff0000u);
                a0 += __uint_as_float(d1 << 16);
                a1 += __uint_as_float(d1 & 0xffff0000u);
            }
            base += cnt; rem -= cnt;
        }
        a0 += __shfl_xor(a0, 32);
        a1 += __shfl_xor(a1, 32);

        // root (pair layout: channels 2*lpair, 2*lpair+1)
        uint rr = *(const uint*)((const char*)r2 + ((size_t)node * 80u + (uint)pre2));
        float r0 = __uint_as_float(rr << 16);
        float r1 = __uint_as_float(rr & 0xffff0000u);

        float inv = 1.0f / (float)(deg > 1 ? deg : 1);
        float l0 = a0 * inv + r0;
        float l1 = a1 * inv + r1;
        if (lpair >= 20) { l0 = -INFINITY; l1 = -INFINITY; }

        float m = fmaxf(l0, l1);
        #pragma unroll
        for (int off = 16; off > 0; off >>= 1)
            m = fmaxf(m, __shfl_xor(m, off));
        float ex = (lpair < 20) ? (expf(l0 - m) + expf(l1 - m)) : 0.0f;
        #pragma unroll
        for (int off = 16; off > 0; off >>= 1)
            ex += __shfl_xor(ex, off);
        float lg = m + logf(ex);
        if (lane < 20) {
            float2 o = make_float2(l0 - lg, l1 - lg);
            *(float2*)(out + (size_t)node * N_CLS + lpair * 2) = o;
        }
    }
}

extern "C" void kernel_launch(void* const* d_in, const int* in_sizes, int n_in,
                              void* d_out, int out_size, void* d_ws, size_t ws_size,
                              hipStream_t stream)
{
    (void)in_sizes; (void)n_in; (void)out_size; (void)ws_size;

    const float* x    = (const float*)d_in[0];
    const int*   ei   = (const int*)d_in[1];      // [2, E]: src row, then dst row
    const float* W1_l = (const float*)d_in[2];
    const float* b1   = (const float*)d_in[3];
    const float* W1_r = (const float*)d_in[4];
    const float* W2_l = (const float*)d_in[5];
    const float* b2   = (const float*)d_in[6];
    const float* W2_r = (const float*)d_in[7];
    float* out = (float*)d_out;

    const int* src = ei;
    const int* dst = ei + N_EDGES;

    // workspace layout (bytes):
    //   row_ptr : [0, 400004)            int[N+1]
    //   cursor  : [512K, +400000)        int[N] (doubles as hist)
    //   partial : [1M, +2048)            int[512]
    //   csr_src : [1M+4K, +5MB+256)      int[N_EDGES+64] (slack)
    //   y1 / y2 : [8M, +12.8MB+128)      bf16[(N+1)*64]; y2 bf16[(N+1)*40] overlays
    //   r1 / r2 : [21M, +12.8MB)         bf16[N*64]; r2 bf16[N*40] overlays (r1 dead)
    //   h       : [34M, +12.8MB)         bf16[N*64]     (max used ~46.8MB)
    char* ws = (char*)d_ws;
    int*            row_ptr = (int*)(ws);
    int*            cursor  = (int*)(ws + (512u << 10));
    int*            partial = (int*)(ws + (1u << 20));
    int*            csr_src = (int*)(ws + (1u << 20) + 4096);
    __hip_bfloat16* y1      = (__hip_bfloat16*)(ws + (8u << 20));
    __hip_bfloat16* y2      = (__hip_bfloat16*)(ws + (8u << 20));
    __hip_bfloat16* r1      = (__hip_bfloat16*)(ws + (21u << 20));
    __hip_bfloat16* r2      = (__hip_bfloat16*)(ws + (21u << 20));
    __hip_bfloat16* h       = (__hip_bfloat16*)(ws + (34u << 20));

    // CSR build (XCD-partitioned)
    hipMemsetAsync(cursor, 0, (size_t)N_NODES * sizeof(int), stream);
    hist_part<<<NCHUNK * 8, 256, 0, stream>>>(dst, cursor, N_EDGES);
    scan_block_sums<<<SCAN_NBLK, 256, 0, stream>>>(cursor, partial, N_NODES);
    scan_partials<<<1, 512, 0, stream>>>(partial, SCAN_NBLK);
    scan_final<<<SCAN_NBLK, 256, 0, stream>>>(cursor, partial, row_ptr, cursor,
                                              N_NODES, N_EDGES);
    fill_part<<<NCHUNK * 8, 256, 0, stream>>>(src, dst, cursor, csr_src, N_EDGES);

    // layer 1
    hipMemsetAsync(y1 + (size_t)N_NODES * 64, 0, 64 * sizeof(__hip_bfloat16), stream);
    gemm1<<<1024, 256, 0, stream>>>(x, W1_l, W1_r, b1, y1, r1, N_NODES);
    gather1<<<1024, 256, 0, stream>>>(y1, r1, row_ptr, csr_src, h, N_NODES);

    // layer 2 (y2/r2 overlay y1/r1 regions; both dead after gather1)
    hipMemsetAsync(y2 + (size_t)N_NODES * N_CLS, 0, N_CLS * sizeof(__hip_bfloat16), stream);
    gemm2<<<1024, 256, 0, stream>>>(h, W2_l, W2_r, b2, y2, r2, N_NODES);
    gather2<<<1024, 256, 0, stream>>>(y2, r2, row_ptr, csr_src, out, N_NODES);
}

// Round 6
// 351.030 us; speedup vs baseline: 1.3134x; 1.3134x over previous
//
#include <hip/hip_runtime.h>
#include <hip/hip_bf16.h>
#include <math.h>

#define N_NODES 100000
#define N_EDGES 1250000
#define D_IN    64
#define D_HID   64
#define N_CLS   40

#define SCAN_NBLK ((N_NODES + 255) / 256)   // 391
#define NPART    8
#define PART_SZ  ((N_NODES + NPART - 1) / NPART)   // 12500
#define NCHUNK   128

typedef unsigned int uint;
typedef __attribute__((ext_vector_type(8))) short bf16x8;
typedef __attribute__((ext_vector_type(4))) float f32x4;

static __device__ __forceinline__ uint pack_bf16x2(float a, float b) {
    unsigned short ua = __builtin_bit_cast(unsigned short, __float2bfloat16(a));
    unsigned short ub = __builtin_bit_cast(unsigned short, __float2bfloat16(b));
    return (uint)ua | ((uint)ub << 16);
}
static __device__ __forceinline__ short f2bf(float f) {
    return (short)__builtin_bit_cast(unsigned short, __float2bfloat16(f));
}

// ---------------------------------------------------------------------------
// CSR build, XCD-partitioned (unchanged from round 5)
// ---------------------------------------------------------------------------
__global__ __launch_bounds__(256) void hist_part(
    const int* __restrict__ dst, int* __restrict__ hist, int n_edges)
{
    const int part  = blockIdx.x & 7;
    const int chunk = blockIdx.x >> 3;
    const int per   = (n_edges + NCHUNK - 1) / NCHUNK;
    const int e0 = chunk * per;
    const int e1 = (e0 + per < n_edges) ? e0 + per : n_edges;
    const int lo = part * PART_SZ, hi = lo + PART_SZ;
    for (int e = e0 + threadIdx.x; e < e1; e += 256) {
        int d = dst[e];
        if (d >= lo && d < hi) atomicAdd(&hist[d], 1);
    }
}

__global__ __launch_bounds__(256) void fill_part(
    const int* __restrict__ src, const int* __restrict__ dst,
    int* __restrict__ cursor, int* __restrict__ csr_src, int n_edges)
{
    const int part  = blockIdx.x & 7;
    const int chunk = blockIdx.x >> 3;
    const int per   = (n_edges + NCHUNK - 1) / NCHUNK;
    const int e0 = chunk * per;
    const int e1 = (e0 + per < n_edges) ? e0 + per : n_edges;
    const int lo = part * PART_SZ, hi = lo + PART_SZ;
    for (int e = e0 + threadIdx.x; e < e1; e += 256) {
        int d = dst[e];
        if (d >= lo && d < hi) {
            int pos = atomicAdd(&cursor[d], 1);
            csr_src[pos] = src[e];
        }
    }
}

__global__ __launch_bounds__(256) void scan_block_sums(
    const int* __restrict__ hist, int* __restrict__ partial, int n)
{
    __shared__ int s[256];
    int i = blockIdx.x * 256 + threadIdx.x;
    s[threadIdx.x] = (i < n) ? hist[i] : 0;
    __syncthreads();
    for (int off = 128; off > 0; off >>= 1) {
        if (threadIdx.x < off) s[threadIdx.x] += s[threadIdx.x + off];
        __syncthreads();
    }
    if (threadIdx.x == 0) partial[blockIdx.x] = s[0];
}

__global__ __launch_bounds__(512) void scan_partials(
    int* __restrict__ partial, int nblk)
{
    __shared__ int s[512];
    int t = threadIdx.x;
    s[t] = (t < nblk) ? partial[t] : 0;
    __syncthreads();
    for (int off = 1; off < 512; off <<= 1) {
        int u = (t >= off) ? s[t - off] : 0;
        __syncthreads();
        s[t] += u;
        __syncthreads();
    }
    if (t < nblk) partial[t] = s[t];   // inclusive
}

__global__ __launch_bounds__(256) void scan_final(
    const int* __restrict__ hist, const int* __restrict__ partial_incl,
    int* __restrict__ row_ptr, int* __restrict__ cursor, int n, int n_edges)
{
    __shared__ int s[256];
    int t = threadIdx.x;
    int i = blockIdx.x * 256 + t;
    int v = (i < n) ? hist[i] : 0;
    s[t] = v;
    __syncthreads();
    for (int off = 1; off < 256; off <<= 1) {
        int u = (t >= off) ? s[t - off] : 0;
        __syncthreads();
        s[t] += u;
        __syncthreads();
    }
    int excl = s[t] - v;
    int base = (blockIdx.x > 0) ? partial_incl[blockIdx.x - 1] : 0;
    if (i < n) {
        row_ptr[i] = base + excl;
        cursor[i]  = base + excl;
    }
    if (i == 0) row_ptr[n] = n_edges;
}

// ---------------------------------------------------------------------------
// MFMA GEMM 1: [y1 | r1] = bf16( x @ [W1_l | W1_r] (+ b1 on r) ).
// Wave tile = 16 nodes x 128 cols: 8 N-tiles x 2 K-steps = 16 MFMA.
// A: A[m=lane&15][k=quad*8+j] (x converted fp32->bf16 inline).
// B: B[k=quad*8+j][n=lane&15], preloaded in VGPRs.
// D: col=lane&15, row=quad*4+reg.
// ---------------------------------------------------------------------------
__global__ __launch_bounds__(256, 3) void gemm1_mfma(
    const float* __restrict__ x,
    const float* __restrict__ W_l, const float* __restrict__ W_r,
    const float* __restrict__ b,
    __hip_bfloat16* __restrict__ y1, __hip_bfloat16* __restrict__ r1,
    int ntiles)
{
    const int lane = threadIdx.x & 63;
    const int m = lane & 15;
    const int q = lane >> 4;

    bf16x8 bfrag[8][2];
    float  biasv[4];
    #pragma unroll
    for (int t = 0; t < 8; ++t) {
        const float* Wsrc = (t < 4) ? W_l : W_r;
        const int c = t * 16 + m - ((t < 4) ? 0 : 64);
        #pragma unroll
        for (int ks = 0; ks < 2; ++ks) {
            bf16x8 f;
            #pragma unroll
            for (int j = 0; j < 8; ++j)
                f[j] = f2bf(Wsrc[(ks * 32 + q * 8 + j) * 64 + c]);
            bfrag[t][ks] = f;
        }
    }
    #pragma unroll
    for (int t = 0; t < 4; ++t) biasv[t] = b[t * 16 + m];

    int wid = blockIdx.x * 4 + (threadIdx.x >> 6);
    const int nw = gridDim.x * 4;
    for (int tile = wid; tile < ntiles; tile += nw) {
        const int node0 = tile * 16;
        const float* xrow = x + (size_t)(node0 + m) * 64 + q * 8;
        bf16x8 afrag[2];
        #pragma unroll
        for (int ks = 0; ks < 2; ++ks) {
            float4 f0 = *(const float4*)(xrow + ks * 32);
            float4 f1 = *(const float4*)(xrow + ks * 32 + 4);
            bf16x8 a;
            a[0] = f2bf(f0.x); a[1] = f2bf(f0.y); a[2] = f2bf(f0.z); a[3] = f2bf(f0.w);
            a[4] = f2bf(f1.x); a[5] = f2bf(f1.y); a[6] = f2bf(f1.z); a[7] = f2bf(f1.w);
            afrag[ks] = a;
        }
        f32x4 acc[8];
        #pragma unroll
        for (int t = 0; t < 8; ++t) acc[t] = (f32x4){0.f, 0.f, 0.f, 0.f};
        #pragma unroll
        for (int ks = 0; ks < 2; ++ks) {
            #pragma unroll
            for (int t = 0; t < 8; ++t)
                acc[t] = __builtin_amdgcn_mfma_f32_16x16x32_bf16(
                    afrag[ks], bfrag[t][ks], acc[t], 0, 0, 0);
        }
        #pragma unroll
        for (int t = 0; t < 8; ++t) {
            #pragma unroll
            for (int r = 0; r < 4; ++r) {
                const size_t row = (size_t)(node0 + q * 4 + r);
                if (t < 4)
                    y1[row * 64 + t * 16 + m] = __float2bfloat16(acc[t][r]);
                else
                    r1[row * 64 + (t - 4) * 16 + m] =
                        __float2bfloat16(acc[t][r] + biasv[t - 4]);
            }
        }
    }
}

// ---------------------------------------------------------------------------
// MFMA GEMM 2: [y2 | r2] = bf16( h @ [W2_l | W2_r] (+ b2 on r) ). 64 -> 80.
// 5 N-tiles x 2 K-steps = 10 MFMA per 16 nodes. Tile 2 straddles the y/r seam.
// ---------------------------------------------------------------------------
__global__ __launch_bounds__(256, 3) void gemm2_mfma(
    const __hip_bfloat16* __restrict__ h,
    const float* __restrict__ W_l, const float* __restrict__ W_r,
    const float* __restrict__ b,
    __hip_bfloat16* __restrict__ y2, __hip_bfloat16* __restrict__ r2,
    int ntiles)
{
    const int lane = threadIdx.x & 63;
    const int m = lane & 15;
    const int q = lane >> 4;

    bf16x8 bfrag[5][2];
    float  biasv[5];
    #pragma unroll
    for (int t = 0; t < 5; ++t) {
        const int g = t * 16 + m;
        const float* Wsrc = (g < N_CLS) ? W_l : W_r;
        const int c = (g < N_CLS) ? g : g - N_CLS;
        #pragma unroll
        for (int ks = 0; ks < 2; ++ks) {
            bf16x8 f;
            #pragma unroll
            for (int j = 0; j < 8; ++j)
                f[j] = f2bf(Wsrc[(ks * 32 + q * 8 + j) * N_CLS + c]);
            bfrag[t][ks] = f;
        }
        biasv[t] = (g >= N_CLS) ? b[g - N_CLS] : 0.0f;
    }

    int wid = blockIdx.x * 4 + (threadIdx.x >> 6);
    const int nw = gridDim.x * 4;
    for (int tile = wid; tile < ntiles; tile += nw) {
        const int node0 = tile * 16;
        const __hip_bfloat16* hrow = h + (size_t)(node0 + m) * 64 + q * 8;
        bf16x8 afrag[2];
        afrag[0] = *(const bf16x8*)(hrow);
        afrag[1] = *(const bf16x8*)(hrow + 32);
        f32x4 acc[5];
        #pragma unroll
        for (int t = 0; t < 5; ++t) acc[t] = (f32x4){0.f, 0.f, 0.f, 0.f};
        #pragma unroll
        for (int ks = 0; ks < 2; ++ks) {
            #pragma unroll
            for (int t = 0; t < 5; ++t)
                acc[t] = __builtin_amdgcn_mfma_f32_16x16x32_bf16(
                    afrag[ks], bfrag[t][ks], acc[t], 0, 0, 0);
        }
        #pragma unroll
        for (int t = 0; t < 5; ++t) {
            const int g = t * 16 + m;
            #pragma unroll
            for (int r = 0; r < 4; ++r) {
                const size_t row = (size_t)(node0 + q * 4 + r);
                float v = acc[t][r] + biasv[t];
                if (g < N_CLS) y2[row * N_CLS + g] = __float2bfloat16(v);
                else           r2[row * N_CLS + (g - N_CLS)] = __float2bfloat16(v);
            }
        }
    }
}

// ---------------------------------------------------------------------------
// Gather 1: h = relu( mean(y1[src]) + r1[node] ) (unchanged from round 5)
// ---------------------------------------------------------------------------
__global__ __launch_bounds__(256, 4) void gather1(
    const __hip_bfloat16* __restrict__ y1,   // [N+1][64], row N zeroed
    const __hip_bfloat16* __restrict__ r1,   // [N][64]
    const int* __restrict__ row_ptr, const int* __restrict__ csr_src,
    __hip_bfloat16* __restrict__ h, int n_nodes)
{
    const int lane = threadIdx.x & 63;
    const int q4  = (lane >> 4) * 4;
    const int pre = (lane & 15) * 8;
    const char* y1c = (const char*)y1;

    const int wave = blockIdx.x * 4 + (threadIdx.x >> 6);
    const int nw   = gridDim.x * 4;

    for (int node = wave; node < n_nodes; node += nw) {
        const int n0  = row_ptr[node];
        const int deg = row_ptr[node + 1] - n0;
        float a0 = 0.f, a1 = 0.f, a2 = 0.f, a3 = 0.f;
        int base = n0, rem = deg;
        while (rem > 0) {
            int cnt = rem < 64 ? rem : 64;
            int idx = csr_src[base + lane];
            if (lane >= cnt) idx = n_nodes;
            int groups = (cnt + 7) & ~7;
            for (int e = 0; e < groups; e += 8) {
                int sel0 = __builtin_amdgcn_ds_bpermute(e * 4 + q4, idx);
                int sel1 = __builtin_amdgcn_ds_bpermute(e * 4 + 16 + q4, idx);
                uint2 d0 = *(const uint2*)(y1c + ((size_t)(uint)sel0 * 128u + (uint)pre));
                uint2 d1 = *(const uint2*)(y1c + ((size_t)(uint)sel1 * 128u + (uint)pre));
                a0 += __uint_as_float(d0.x << 16);
                a1 += __uint_as_float(d0.x & 0xffff0000u);
                a2 += __uint_as_float(d0.y << 16);
                a3 += __uint_as_float(d0.y & 0xffff0000u);
                a0 += __uint_as_float(d1.x << 16);
                a1 += __uint_as_float(d1.x & 0xffff0000u);
                a2 += __uint_as_float(d1.y << 16);
                a3 += __uint_as_float(d1.y & 0xffff0000u);
            }
            base += cnt; rem -= cnt;
        }
        a0 += __shfl_xor(a0, 16); a0 += __shfl_xor(a0, 32);
        a1 += __shfl_xor(a1, 16); a1 += __shfl_xor(a1, 32);
        a2 += __shfl_xor(a2, 16); a2 += __shfl_xor(a2, 32);
        a3 += __shfl_xor(a3, 16); a3 += __shfl_xor(a3, 32);

        uint2 rr = *(const uint2*)((const char*)r1 + ((size_t)node * 128u + (uint)pre));
        float r0  = __uint_as_float(rr.x << 16);
        float r1v = __uint_as_float(rr.x & 0xffff0000u);
        float r2v = __uint_as_float(rr.y << 16);
        float r3  = __uint_as_float(rr.y & 0xffff0000u);

        float inv = 1.0f / (float)(deg > 1 ? deg : 1);
        float v0 = a0 * inv + r0;  v0 = v0 > 0.f ? v0 : 0.f;
        float v1 = a1 * inv + r1v; v1 = v1 > 0.f ? v1 : 0.f;
        float v2 = a2 * inv + r2v; v2 = v2 > 0.f ? v2 : 0.f;
        float v3 = a3 * inv + r3;  v3 = v3 > 0.f ? v3 : 0.f;

        if (lane < 16) {
            uint2 o;
            o.x = pack_bf16x2(v0, v1);
            o.y = pack_bf16x2(v2, v3);
            *(uint2*)((char*)h + ((size_t)node * 128u + (uint)pre)) = o;
        }
    }
}

// ---------------------------------------------------------------------------
// Gather 2: out = logsoftmax( mean(y2[src]) + r2[node] ) (unchanged)
// ---------------------------------------------------------------------------
__global__ __launch_bounds__(256, 4) void gather2(
    const __hip_bfloat16* __restrict__ y2,   // [N+1][40], row N zeroed
    const __hip_bfloat16* __restrict__ r2,   // [N][40]
    const int* __restrict__ row_ptr, const int* __restrict__ csr_src,
    float* __restrict__ out, int n_nodes)
{
    const int lane  = threadIdx.x & 63;
    const int lpair = lane & 31;
    const int p2    = (lane >> 5) * 4;
    const int pre2  = (lpair < 20 ? lpair : 19) * 4;
    const char* y2c = (const char*)y2;

    const int wave = blockIdx.x * 4 + (threadIdx.x >> 6);
    const int nw   = gridDim.x * 4;

    for (int node = wave; node < n_nodes; node += nw) {
        const int n0  = row_ptr[node];
        const int deg = row_ptr[node + 1] - n0;
        float a0 = 0.f, a1 = 0.f;
        int base = n0, rem = deg;
        while (rem > 0) {
            int cnt = rem < 64 ? rem : 64;
            int idx = csr_src[base + lane];
            if (lane >= cnt) idx = n_nodes;
            int groups = (cnt + 3) & ~3;
            for (int e = 0; e < groups; e += 4) {
                int sel0 = __builtin_amdgcn_ds_bpermute(e * 4 + p2, idx);
                int sel1 = __builtin_amdgcn_ds_bpermute(e * 4 + 8 + p2, idx);
                uint d0 = *(const uint*)(y2c + ((size_t)(uint)sel0 * 80u + (uint)pre2));
                uint d1 = *(const uint*)(y2c + ((size_t)(uint)sel1 * 80u + (uint)pre2));
                a0 += __uint_as_float(d0 << 16);
                a1 += __uint_as_float(d0 & 0xffff0000u);
                a0 += __uint_as_float(d1 << 16);
                a1 += __uint_as_float(d1 & 0xffff0000u);
            }
            base += cnt; rem -= cnt;
        }
        a0 += __shfl_xor(a0, 32);
        a1 += __shfl_xor(a1, 32);

        uint rr = *(const uint*)((const char*)r2 + ((size_t)node * 80u + (uint)pre2));
        float r0 = __uint_as_float(rr << 16);
        float r1 = __uint_as_float(rr & 0xffff0000u);

        float inv = 1.0f / (float)(deg > 1 ? deg : 1);
        float l0 = a0 * inv + r0;
        float l1 = a1 * inv + r1;
        if (lpair >= 20) { l0 = -INFINITY; l1 = -INFINITY; }

        float m = fmaxf(l0, l1);
        #pragma unroll
        for (int off = 16; off > 0; off >>= 1)
            m = fmaxf(m, __shfl_xor(m, off));
        float ex = (lpair < 20) ? (expf(l0 - m) + expf(l1 - m)) : 0.0f;
        #pragma unroll
        for (int off = 16; off > 0; off >>= 1)
            ex += __shfl_xor(ex, off);
        float lg = m + logf(ex);
        if (lane < 20) {
            float2 o = make_float2(l0 - lg, l1 - lg);
            *(float2*)(out + (size_t)node * N_CLS + lpair * 2) = o;
        }
    }
}

extern "C" void kernel_launch(void* const* d_in, const int* in_sizes, int n_in,
                              void* d_out, int out_size, void* d_ws, size_t ws_size,
                              hipStream_t stream)
{
    (void)in_sizes; (void)n_in; (void)out_size; (void)ws_size;

    const float* x    = (const float*)d_in[0];
    const int*   ei   = (const int*)d_in[1];      // [2, E]: src row, then dst row
    const float* W1_l = (const float*)d_in[2];
    const float* b1   = (const float*)d_in[3];
    const float* W1_r = (const float*)d_in[4];
    const float* W2_l = (const float*)d_in[5];
    const float* b2   = (const float*)d_in[6];
    const float* W2_r = (const float*)d_in[7];
    float* out = (float*)d_out;

    const int* src = ei;
    const int* dst = ei + N_EDGES;

    // workspace layout (bytes):
    //   row_ptr : [0, 400004)            int[N+1]
    //   cursor  : [512K, +400000)        int[N] (doubles as hist)
    //   partial : [1M, +2048)            int[512]
    //   csr_src : [1M+4K, +5MB+256)      int[N_EDGES+64] (slack)
    //   y1 / y2 : [8M, +12.8MB+128)      bf16[(N+1)*64]; y2 bf16[(N+1)*40] overlays
    //   r1 / r2 : [21M, +12.8MB)         bf16[N*64]; r2 bf16[N*40] overlays
    //   h       : [34M, +12.8MB)
    char* ws = (char*)d_ws;
    int*            row_ptr = (int*)(ws);
    int*            cursor  = (int*)(ws + (512u << 10));
    int*            partial = (int*)(ws + (1u << 20));
    int*            csr_src = (int*)(ws + (1u << 20) + 4096);
    __hip_bfloat16* y1      = (__hip_bfloat16*)(ws + (8u << 20));
    __hip_bfloat16* y2      = (__hip_bfloat16*)(ws + (8u << 20));
    __hip_bfloat16* r1      = (__hip_bfloat16*)(ws + (21u << 20));
    __hip_bfloat16* r2      = (__hip_bfloat16*)(ws + (21u << 20));
    __hip_bfloat16* h       = (__hip_bfloat16*)(ws + (34u << 20));

    // CSR build (XCD-partitioned)
    hipMemsetAsync(cursor, 0, (size_t)N_NODES * sizeof(int), stream);
    hist_part<<<NCHUNK * 8, 256, 0, stream>>>(dst, cursor, N_EDGES);
    scan_block_sums<<<SCAN_NBLK, 256, 0, stream>>>(cursor, partial, N_NODES);
    scan_partials<<<1, 512, 0, stream>>>(partial, SCAN_NBLK);
    scan_final<<<SCAN_NBLK, 256, 0, stream>>>(cursor, partial, row_ptr, cursor,
                                              N_NODES, N_EDGES);
    fill_part<<<NCHUNK * 8, 256, 0, stream>>>(src, dst, cursor, csr_src, N_EDGES);

    const int ntiles = N_NODES / 16;   // 6250, exact

    // layer 1
    hipMemsetAsync(y1 + (size_t)N_NODES * 64, 0, 64 * sizeof(__hip_bfloat16), stream);
    gemm1_mfma<<<512, 256, 0, stream>>>(x, W1_l, W1_r, b1, y1, r1, ntiles);
    gather1<<<1024, 256, 0, stream>>>(y1, r1, row_ptr, csr_src, h, N_NODES);

    // layer 2 (y2/r2 overlay y1/r1; both dead after gather1)
    hipMemsetAsync(y2 + (size_t)N_NODES * N_CLS, 0, N_CLS * sizeof(__hip_bfloat16), stream);
    gemm2_mfma<<<512, 256, 0, stream>>>(h, W2_l, W2_r, b2, y2, r2, ntiles);
    gather2<<<1024, 256, 0, stream>>>(y2, r2, row_ptr, csr_src, out, N_NODES);
}

// Round 7
// 295.297 us; speedup vs baseline: 1.5613x; 1.1887x over previous
//
#include <hip/hip_runtime.h>
#include <hip/hip_bf16.h>
#include <math.h>

#define N_NODES 100000
#define N_EDGES 1250000
#define D_IN    64
#define D_HID   64
#define N_CLS   40

#define SCAN_NBLK ((N_NODES + 255) / 256)   // 391
#define NPART    8
#define PART_SZ  ((N_NODES + NPART - 1) / NPART)   // 12500
#define NCHUNK   256

typedef unsigned int uint;
typedef __attribute__((ext_vector_type(8))) short bf16x8;
typedef __attribute__((ext_vector_type(4))) float f32x4;

static __device__ __forceinline__ uint pack_bf16x2(float a, float b) {
    unsigned short ua = __builtin_bit_cast(unsigned short, __float2bfloat16(a));
    unsigned short ub = __builtin_bit_cast(unsigned short, __float2bfloat16(b));
    return (uint)ua | ((uint)ub << 16);
}
static __device__ __forceinline__ short f2bf(float f) {
    return (short)__builtin_bit_cast(unsigned short, __float2bfloat16(f));
}

// ---------------------------------------------------------------------------
// CSR build, XCD-partitioned
// ---------------------------------------------------------------------------
__global__ __launch_bounds__(256) void hist_part(
    const int* __restrict__ dst, int* __restrict__ hist, int n_edges)
{
    const int part  = blockIdx.x & 7;
    const int chunk = blockIdx.x >> 3;
    const int per   = (n_edges + NCHUNK - 1) / NCHUNK;
    const int e0 = chunk * per;
    const int e1 = (e0 + per < n_edges) ? e0 + per : n_edges;
    const int lo = part * PART_SZ, hi = lo + PART_SZ;
    for (int e = e0 + threadIdx.x; e < e1; e += 256) {
        int d = dst[e];
        if (d >= lo && d < hi) atomicAdd(&hist[d], 1);
    }
}

__global__ __launch_bounds__(256) void fill_part(
    const int* __restrict__ src, const int* __restrict__ dst,
    int* __restrict__ cursor, int* __restrict__ csr_src, int n_edges)
{
    const int part  = blockIdx.x & 7;
    const int chunk = blockIdx.x >> 3;
    const int per   = (n_edges + NCHUNK - 1) / NCHUNK;
    const int e0 = chunk * per;
    const int e1 = (e0 + per < n_edges) ? e0 + per : n_edges;
    const int lo = part * PART_SZ, hi = lo + PART_SZ;
    for (int e = e0 + threadIdx.x; e < e1; e += 256) {
        int d = dst[e];
        if (d >= lo && d < hi) {
            int pos = atomicAdd(&cursor[d], 1);
            csr_src[pos] = src[e];
        }
    }
}

__global__ __launch_bounds__(256) void scan_block_sums(
    const int* __restrict__ hist, int* __restrict__ partial, int n)
{
    __shared__ int s[256];
    int i = blockIdx.x * 256 + threadIdx.x;
    s[threadIdx.x] = (i < n) ? hist[i] : 0;
    __syncthreads();
    for (int off = 128; off > 0; off >>= 1) {
        if (threadIdx.x < off) s[threadIdx.x] += s[threadIdx.x + off];
        __syncthreads();
    }
    if (threadIdx.x == 0) partial[blockIdx.x] = s[0];
}

__global__ __launch_bounds__(512) void scan_partials(
    int* __restrict__ partial, int nblk)
{
    __shared__ int s[512];
    int t = threadIdx.x;
    s[t] = (t < nblk) ? partial[t] : 0;
    __syncthreads();
    for (int off = 1; off < 512; off <<= 1) {
        int u = (t >= off) ? s[t - off] : 0;
        __syncthreads();
        s[t] += u;
        __syncthreads();
    }
    if (t < nblk) partial[t] = s[t];   // inclusive
}

__global__ __launch_bounds__(256) void scan_final(
    const int* __restrict__ hist, const int* __restrict__ partial_incl,
    int* __restrict__ row_ptr, int* __restrict__ cursor, int n, int n_edges)
{
    __shared__ int s[256];
    int t = threadIdx.x;
    int i = blockIdx.x * 256 + t;
    int v = (i < n) ? hist[i] : 0;
    s[t] = v;
    __syncthreads();
    for (int off = 1; off < 256; off <<= 1) {
        int u = (t >= off) ? s[t - off] : 0;
        __syncthreads();
        s[t] += u;
        __syncthreads();
    }
    int excl = s[t] - v;
    int base = (blockIdx.x > 0) ? partial_incl[blockIdx.x - 1] : 0;
    if (i < n) {
        row_ptr[i] = base + excl;
        cursor[i]  = base + excl;
    }
    if (i == 0) row_ptr[n] = n_edges;
}

// ---------------------------------------------------------------------------
// MFMA GEMM 1: [y1 | r1] = bf16( x @ [W1_l | W1_r] (+ b1 on r) ).
// ---------------------------------------------------------------------------
__global__ __launch_bounds__(256, 3) void gemm1_mfma(
    const float* __restrict__ x,
    const float* __restrict__ W_l, const float* __restrict__ W_r,
    const float* __restrict__ b,
    __hip_bfloat16* __restrict__ y1, __hip_bfloat16* __restrict__ r1,
    int ntiles)
{
    const int lane = threadIdx.x & 63;
    const int m = lane & 15;
    const int q = lane >> 4;

    bf16x8 bfrag[8][2];
    float  biasv[4];
    #pragma unroll
    for (int t = 0; t < 8; ++t) {
        const float* Wsrc = (t < 4) ? W_l : W_r;
        const int c = t * 16 + m - ((t < 4) ? 0 : 64);
        #pragma unroll
        for (int ks = 0; ks < 2; ++ks) {
            bf16x8 f;
            #pragma unroll
            for (int j = 0; j < 8; ++j)
                f[j] = f2bf(Wsrc[(ks * 32 + q * 8 + j) * 64 + c]);
            bfrag[t][ks] = f;
        }
    }
    #pragma unroll
    for (int t = 0; t < 4; ++t) biasv[t] = b[t * 16 + m];

    int wid = blockIdx.x * 4 + (threadIdx.x >> 6);
    const int nw = gridDim.x * 4;
    for (int tile = wid; tile < ntiles; tile += nw) {
        const int node0 = tile * 16;
        const float* xrow = x + (size_t)(node0 + m) * 64 + q * 8;
        bf16x8 afrag[2];
        #pragma unroll
        for (int ks = 0; ks < 2; ++ks) {
            float4 f0 = *(const float4*)(xrow + ks * 32);
            float4 f1 = *(const float4*)(xrow + ks * 32 + 4);
            bf16x8 a;
            a[0] = f2bf(f0.x); a[1] = f2bf(f0.y); a[2] = f2bf(f0.z); a[3] = f2bf(f0.w);
            a[4] = f2bf(f1.x); a[5] = f2bf(f1.y); a[6] = f2bf(f1.z); a[7] = f2bf(f1.w);
            afrag[ks] = a;
        }
        f32x4 acc[8];
        #pragma unroll
        for (int t = 0; t < 8; ++t) acc[t] = (f32x4){0.f, 0.f, 0.f, 0.f};
        #pragma unroll
        for (int ks = 0; ks < 2; ++ks) {
            #pragma unroll
            for (int t = 0; t < 8; ++t)
                acc[t] = __builtin_amdgcn_mfma_f32_16x16x32_bf16(
                    afrag[ks], bfrag[t][ks], acc[t], 0, 0, 0);
        }
        #pragma unroll
        for (int t = 0; t < 8; ++t) {
            #pragma unroll
            for (int r = 0; r < 4; ++r) {
                const size_t row = (size_t)(node0 + q * 4 + r);
                if (t < 4)
                    y1[row * 64 + t * 16 + m] = __float2bfloat16(acc[t][r]);
                else
                    r1[row * 64 + (t - 4) * 16 + m] =
                        __float2bfloat16(acc[t][r] + biasv[t - 4]);
            }
        }
    }
}

// ---------------------------------------------------------------------------
// MFMA GEMM 2: [y2 | r2] = bf16( h @ [W2_l | W2_r] (+ b2 on r) ). 64 -> 80.
// ---------------------------------------------------------------------------
__global__ __launch_bounds__(256, 3) void gemm2_mfma(
    const __hip_bfloat16* __restrict__ h,
    const float* __restrict__ W_l, const float* __restrict__ W_r,
    const float* __restrict__ b,
    __hip_bfloat16* __restrict__ y2, __hip_bfloat16* __restrict__ r2,
    int ntiles)
{
    const int lane = threadIdx.x & 63;
    const int m = lane & 15;
    const int q = lane >> 4;

    bf16x8 bfrag[5][2];
    float  biasv[5];
    #pragma unroll
    for (int t = 0; t < 5; ++t) {
        const int g = t * 16 + m;
        const float* Wsrc = (g < N_CLS) ? W_l : W_r;
        const int c = (g < N_CLS) ? g : g - N_CLS;
        #pragma unroll
        for (int ks = 0; ks < 2; ++ks) {
            bf16x8 f;
            #pragma unroll
            for (int j = 0; j < 8; ++j)
                f[j] = f2bf(Wsrc[(ks * 32 + q * 8 + j) * N_CLS + c]);
            bfrag[t][ks] = f;
        }
        biasv[t] = (g >= N_CLS) ? b[g - N_CLS] : 0.0f;
    }

    int wid = blockIdx.x * 4 + (threadIdx.x >> 6);
    const int nw = gridDim.x * 4;
    for (int tile = wid; tile < ntiles; tile += nw) {
        const int node0 = tile * 16;
        const __hip_bfloat16* hrow = h + (size_t)(node0 + m) * 64 + q * 8;
        bf16x8 afrag[2];
        afrag[0] = *(const bf16x8*)(hrow);
        afrag[1] = *(const bf16x8*)(hrow + 32);
        f32x4 acc[5];
        #pragma unroll
        for (int t = 0; t < 5; ++t) acc[t] = (f32x4){0.f, 0.f, 0.f, 0.f};
        #pragma unroll
        for (int ks = 0; ks < 2; ++ks) {
            #pragma unroll
            for (int t = 0; t < 5; ++t)
                acc[t] = __builtin_amdgcn_mfma_f32_16x16x32_bf16(
                    afrag[ks], bfrag[t][ks], acc[t], 0, 0, 0);
        }
        #pragma unroll
        for (int t = 0; t < 5; ++t) {
            const int g = t * 16 + m;
            #pragma unroll
            for (int r = 0; r < 4; ++r) {
                const size_t row = (size_t)(node0 + q * 4 + r);
                float v = acc[t][r] + biasv[t];
                if (g < N_CLS) y2[row * N_CLS + g] = __float2bfloat16(v);
                else           r2[row * N_CLS + (g - N_CLS)] = __float2bfloat16(v);
            }
        }
    }
}

// ---------------------------------------------------------------------------
// Gather 1: h = relu( mean(y1[src]) + r1[node] ).
// 16 edges per inner iteration: 4 independent wave-loads in flight.
// ---------------------------------------------------------------------------
__global__ __launch_bounds__(256, 8) void gather1(
    const __hip_bfloat16* __restrict__ y1,   // [N+1][64], row N zeroed
    const __hip_bfloat16* __restrict__ r1,   // [N][64]
    const int* __restrict__ row_ptr, const int* __restrict__ csr_src,
    __hip_bfloat16* __restrict__ h, int n_nodes)
{
    const int lane = threadIdx.x & 63;
    const int q4  = (lane >> 4) * 4;
    const int pre = (lane & 15) * 8;
    const char* y1c = (const char*)y1;

    const int wave = blockIdx.x * 4 + (threadIdx.x >> 6);
    const int nw   = gridDim.x * 4;

    for (int node = wave; node < n_nodes; node += nw) {
        const int n0  = row_ptr[node];
        const int deg = row_ptr[node + 1] - n0;
        float a0 = 0.f, a1 = 0.f, a2 = 0.f, a3 = 0.f;
        int base = n0, rem = deg;
        while (rem > 0) {
            int cnt = rem < 64 ? rem : 64;
            int idx = csr_src[base + lane];
            if (lane >= cnt) idx = n_nodes;
            int groups = (cnt + 15) & ~15;
            for (int e = 0; e < groups; e += 16) {
                int sel0 = __builtin_amdgcn_ds_bpermute(e * 4      + q4, idx);
                int sel1 = __builtin_amdgcn_ds_bpermute(e * 4 + 16 + q4, idx);
                int sel2 = __builtin_amdgcn_ds_bpermute(e * 4 + 32 + q4, idx);
                int sel3 = __builtin_amdgcn_ds_bpermute(e * 4 + 48 + q4, idx);
                uint2 d0 = *(const uint2*)(y1c + ((size_t)(uint)sel0 * 128u + (uint)pre));
                uint2 d1 = *(const uint2*)(y1c + ((size_t)(uint)sel1 * 128u + (uint)pre));
                uint2 d2 = *(const uint2*)(y1c + ((size_t)(uint)sel2 * 128u + (uint)pre));
                uint2 d3 = *(const uint2*)(y1c + ((size_t)(uint)sel3 * 128u + (uint)pre));
                a0 += __uint_as_float(d0.x << 16) + __uint_as_float(d1.x << 16)
                    + __uint_as_float(d2.x << 16) + __uint_as_float(d3.x << 16);
                a1 += __uint_as_float(d0.x & 0xffff0000u) + __uint_as_float(d1.x & 0xffff0000u)
                    + __uint_as_float(d2.x & 0xffff0000u) + __uint_as_float(d3.x & 0xffff0000u);
                a2 += __uint_as_float(d0.y << 16) + __uint_as_float(d1.y << 16)
                    + __uint_as_float(d2.y << 16) + __uint_as_float(d3.y << 16);
                a3 += __uint_as_float(d0.y & 0xffff0000u) + __uint_as_float(d1.y & 0xffff0000u)
                    + __uint_as_float(d2.y & 0xffff0000u) + __uint_as_float(d3.y & 0xffff0000u);
            }
            base += cnt; rem -= cnt;
        }
        a0 += __shfl_xor(a0, 16); a0 += __shfl_xor(a0, 32);
        a1 += __shfl_xor(a1, 16); a1 += __shfl_xor(a1, 32);
        a2 += __shfl_xor(a2, 16); a2 += __shfl_xor(a2, 32);
        a3 += __shfl_xor(a3, 16); a3 += __shfl_xor(a3, 32);

        uint2 rr = *(const uint2*)((const char*)r1 + ((size_t)node * 128u + (uint)pre));
        float r0  = __uint_as_float(rr.x << 16);
        float r1v = __uint_as_float(rr.x & 0xffff0000u);
        float r2v = __uint_as_float(rr.y << 16);
        float r3  = __uint_as_float(rr.y & 0xffff0000u);

        float inv = 1.0f / (float)(deg > 1 ? deg : 1);
        float v0 = a0 * inv + r0;  v0 = v0 > 0.f ? v0 : 0.f;
        float v1 = a1 * inv + r1v; v1 = v1 > 0.f ? v1 : 0.f;
        float v2 = a2 * inv + r2v; v2 = v2 > 0.f ? v2 : 0.f;
        float v3 = a3 * inv + r3;  v3 = v3 > 0.f ? v3 : 0.f;

        if (lane < 16) {
            uint2 o;
            o.x = pack_bf16x2(v0, v1);
            o.y = pack_bf16x2(v2, v3);
            *(uint2*)((char*)h + ((size_t)node * 128u + (uint)pre)) = o;
        }
    }
}

// ---------------------------------------------------------------------------
// Gather 2: out = logsoftmax( mean(y2[src]) + r2[node] ).
// 8 edges per inner iteration: 4 independent wave-loads in flight.
// ---------------------------------------------------------------------------
__global__ __launch_bounds__(256, 8) void gather2(
    const __hip_bfloat16* __restrict__ y2,   // [N+1][40], row N zeroed
    const __hip_bfloat16* __restrict__ r2,   // [N][40]
    const int* __restrict__ row_ptr, const int* __restrict__ csr_src,
    float* __restrict__ out, int n_nodes)
{
    const int lane  = threadIdx.x & 63;
    const int lpair = lane & 31;
    const int p2    = (lane >> 5) * 4;
    const int pre2  = (lpair < 20 ? lpair : 19) * 4;
    const char* y2c = (const char*)y2;

    const int wave = blockIdx.x * 4 + (threadIdx.x >> 6);
    const int nw   = gridDim.x * 4;

    for (int node = wave; node < n_nodes; node += nw) {
        const int n0  = row_ptr[node];
        const int deg = row_ptr[node + 1] - n0;
        float a0 = 0.f, a1 = 0.f;
        int base = n0, rem = deg;
        while (rem > 0) {
            int cnt = rem < 64 ? rem : 64;
            int idx = csr_src[base + lane];
            if (lane >= cnt) idx = n_nodes;
            int groups = (cnt + 7) & ~7;
            for (int e = 0; e < groups; e += 8) {
                int sel0 = __builtin_amdgcn_ds_bpermute(e * 4      + p2, idx);
                int sel1 = __builtin_amdgcn_ds_bpermute(e * 4 +  8 + p2, idx);
                int sel2 = __builtin_amdgcn_ds_bpermute(e * 4 + 16 + p2, idx);
                int sel3 = __builtin_amdgcn_ds_bpermute(e * 4 + 24 + p2, idx);
                uint d0 = *(const uint*)(y2c + ((size_t)(uint)sel0 * 80u + (uint)pre2));
                uint d1 = *(const uint*)(y2c + ((size_t)(uint)sel1 * 80u + (uint)pre2));
                uint d2 = *(const uint*)(y2c + ((size_t)(uint)sel2 * 80u + (uint)pre2));
                uint d3 = *(const uint*)(y2c + ((size_t)(uint)sel3 * 80u + (uint)pre2));
                a0 += __uint_as_float(d0 << 16) + __uint_as_float(d1 << 16)
                    + __uint_as_float(d2 << 16) + __uint_as_float(d3 << 16);
                a1 += __uint_as_float(d0 & 0xffff0000u) + __uint_as_float(d1 & 0xffff0000u)
                    + __uint_as_float(d2 & 0xffff0000u) + __uint_as_float(d3 & 0xffff0000u);
            }
            base += cnt; rem -= cnt;
        }
        a0 += __shfl_xor(a0, 32);
        a1 += __shfl_xor(a1, 32);

        uint rr = *(const uint*)((const char*)r2 + ((size_t)node * 80u + (uint)pre2));
        float r0 = __uint_as_float(rr << 16);
        float r1 = __uint_as_float(rr & 0xffff0000u);

        float inv = 1.0f / (float)(deg > 1 ? deg : 1);
        float l0 = a0 * inv + r0;
        float l1 = a1 * inv + r1;
        if (lpair >= 20) { l0 = -INFINITY; l1 = -INFINITY; }

        float m = fmaxf(l0, l1);
        #pragma unroll
        for (int off = 16; off > 0; off >>= 1)
            m = fmaxf(m, __shfl_xor(m, off));
        float ex = (lpair < 20) ? (expf(l0 - m) + expf(l1 - m)) : 0.0f;
        #pragma unroll
        for (int off = 16; off > 0; off >>= 1)
            ex += __shfl_xor(ex, off);
        float lg = m + logf(ex);
        if (lane < 20) {
            float2 o = make_float2(l0 - lg, l1 - lg);
            *(float2*)(out + (size_t)node * N_CLS + lpair * 2) = o;
        }
    }
}

extern "C" void kernel_launch(void* const* d_in, const int* in_sizes, int n_in,
                              void* d_out, int out_size, void* d_ws, size_t ws_size,
                              hipStream_t stream)
{
    (void)in_sizes; (void)n_in; (void)out_size; (void)ws_size;

    const float* x    = (const float*)d_in[0];
    const int*   ei   = (const int*)d_in[1];      // [2, E]: src row, then dst row
    const float* W1_l = (const float*)d_in[2];
    const float* b1   = (const float*)d_in[3];
    const float* W1_r = (const float*)d_in[4];
    const float* W2_l = (const float*)d_in[5];
    const float* b2   = (const float*)d_in[6];
    const float* W2_r = (const float*)d_in[7];
    float* out = (float*)d_out;

    const int* src = ei;
    const int* dst = ei + N_EDGES;

    char* ws = (char*)d_ws;
    int*            row_ptr = (int*)(ws);
    int*            cursor  = (int*)(ws + (512u << 10));
    int*            partial = (int*)(ws + (1u << 20));
    int*            csr_src = (int*)(ws + (1u << 20) + 4096);
    __hip_bfloat16* y1      = (__hip_bfloat16*)(ws + (8u << 20));
    __hip_bfloat16* y2      = (__hip_bfloat16*)(ws + (8u << 20));
    __hip_bfloat16* r1      = (__hip_bfloat16*)(ws + (21u << 20));
    __hip_bfloat16* r2      = (__hip_bfloat16*)(ws + (21u << 20));
    __hip_bfloat16* h       = (__hip_bfloat16*)(ws + (34u << 20));

    // CSR build (XCD-partitioned)
    hipMemsetAsync(cursor, 0, (size_t)N_NODES * sizeof(int), stream);
    hist_part<<<NCHUNK * 8, 256, 0, stream>>>(dst, cursor, N_EDGES);
    scan_block_sums<<<SCAN_NBLK, 256, 0, stream>>>(cursor, partial, N_NODES);
    scan_partials<<<1, 512, 0, stream>>>(partial, SCAN_NBLK);
    scan_final<<<SCAN_NBLK, 256, 0, stream>>>(cursor, partial, row_ptr, cursor,
                                              N_NODES, N_EDGES);
    fill_part<<<NCHUNK * 8, 256, 0, stream>>>(src, dst, cursor, csr_src, N_EDGES);

    const int ntiles = N_NODES / 16;   // 6250, exact

    // layer 1
    hipMemsetAsync(y1 + (size_t)N_NODES * 64, 0, 64 * sizeof(__hip_bfloat16), stream);
    gemm1_mfma<<<512, 256, 0, stream>>>(x, W1_l, W1_r, b1, y1, r1, ntiles);
    gather1<<<2048, 256, 0, stream>>>(y1, r1, row_ptr, csr_src, h, N_NODES);

    // layer 2 (y2/r2 overlay y1/r1; both dead after gather1)
    hipMemsetAsync(y2 + (size_t)N_NODES * N_CLS, 0, N_CLS * sizeof(__hip_bfloat16), stream);
    gemm2_mfma<<<512, 256, 0, stream>>>(h, W2_l, W2_r, b2, y2, r2, ntiles);
    gather2<<<2048, 256, 0, stream>>>(y2, r2, row_ptr, csr_src, out, N_NODES);
}